// Round 1
// 1820.628 us; speedup vs baseline: 2.4193x; 2.4193x over previous
//
#include <hip/hip_runtime.h>

// OutputPPBlock: out[n][h] = sum_{e: i[e]==n} (rbf[e] . W[h]) * x[e][h]
// E=2,000,000 edges, HIDDEN=128, NUM_RADIAL=6, NUM_NODES=100,000.
//
// Round 1: scatter -> gather. The atomic baseline moved 4.66 GB (WRITE_SIZE
// 4.10 GB = 16 B per dword atomic, 256M atomics @ ~76G/s was the limiter).
// New plan: on-device counting sort of edges by node (hist + scan + scatter
// of edge IDs only), then one 64-lane wave per node gathers its edge list,
// accumulates in registers, writes each out row exactly once. No atomics on
// the 128-wide payload; only 4M cheap int atomics on a 400 KB counter array.

constexpr int HIDDEN = 128;
constexpr int NRAD   = 6;

// ---------------- fallback: atomic scatter (if workspace too small) --------
__global__ __launch_bounds__(256) void msg_scatter_kernel(
    const float* __restrict__ x,
    const float* __restrict__ rbf,
    const float* __restrict__ W,
    const int*   __restrict__ idx,
    float*       __restrict__ out,
    int E)
{
    __shared__ float sW[HIDDEN * NRAD];
    for (int t = threadIdx.x; t < HIDDEN * NRAD; t += blockDim.x) sW[t] = W[t];
    __syncthreads();

    const int lane = threadIdx.x & 31;
    const int egrp = threadIdx.x >> 5;
    const int epb  = blockDim.x >> 5;
    const int h0   = lane << 2;

    float w[4][NRAD];
#pragma unroll
    for (int j = 0; j < 4; ++j)
#pragma unroll
        for (int r = 0; r < NRAD; ++r)
            w[j][r] = sW[(h0 + j) * NRAD + r];

    for (int e = blockIdx.x * epb + egrp; e < E; e += gridDim.x * epb) {
        const float* rb = rbf + (size_t)e * NRAD;
        const float r0 = rb[0], r1 = rb[1], r2 = rb[2],
                    r3 = rb[3], r4 = rb[4], r5 = rb[5];
        float c[4];
#pragma unroll
        for (int j = 0; j < 4; ++j)
            c[j] = w[j][0] * r0 + w[j][1] * r1 + w[j][2] * r2
                 + w[j][3] * r3 + w[j][4] * r4 + w[j][5] * r5;
        const float4 xv = *reinterpret_cast<const float4*>(
            x + (size_t)e * HIDDEN + h0);
        const int node = idx[e];
        float* o = out + (size_t)node * HIDDEN + h0;
        atomicAdd(o + 0, c[0] * xv.x);
        atomicAdd(o + 1, c[1] * xv.y);
        atomicAdd(o + 2, c[2] * xv.z);
        atomicAdd(o + 3, c[3] * xv.w);
    }
}

// ---------------- pass 1: degree histogram ---------------------------------
__global__ __launch_bounds__(256) void hist_kernel(
    const int* __restrict__ idx, int* __restrict__ counts, int E)
{
    const int stride = gridDim.x * blockDim.x;
    for (int e = blockIdx.x * blockDim.x + threadIdx.x; e < E; e += stride)
        atomicAdd(&counts[idx[e]], 1);
}

// ---------------- pass 2: exclusive prefix sum (single 1024-thread block) --
// 8 elems/thread -> 8192/iter, 13 iters over N=100K. Writes offs (exclusive)
// and a second copy (cursor) for the scatter pass. offs[N] = E.
__global__ __launch_bounds__(1024) void scan_kernel(
    int* __restrict__ offs, int* __restrict__ cursor, int N)
{
    __shared__ int tsum[1024];
    __shared__ int s_carry;
    if (threadIdx.x == 0) s_carry = 0;
    __syncthreads();

    for (int base = 0; base < N; base += 8192) {
        const int i0 = base + (int)threadIdx.x * 8;
        int v[8];
        int s = 0;
#pragma unroll
        for (int j = 0; j < 8; ++j) {
            const int i = i0 + j;
            v[j] = (i < N) ? offs[i] : 0;
            s += v[j];
        }
        tsum[threadIdx.x] = s;
        __syncthreads();
        for (int off = 1; off < 1024; off <<= 1) {
            const int t = (threadIdx.x >= (unsigned)off) ? tsum[threadIdx.x - off] : 0;
            __syncthreads();
            tsum[threadIdx.x] += t;
            __syncthreads();
        }
        int excl = tsum[threadIdx.x] - s + s_carry;
#pragma unroll
        for (int j = 0; j < 8; ++j) {
            const int i = i0 + j;
            if (i < N) { offs[i] = excl; cursor[i] = excl; }
            excl += v[j];
        }
        __syncthreads();
        if (threadIdx.x == 1023) s_carry += tsum[1023];
        __syncthreads();
    }
    if (threadIdx.x == 0) offs[N] = s_carry;
}

// ---------------- pass 3: scatter edge ids into sorted order ---------------
__global__ __launch_bounds__(256) void scatter_kernel(
    const int* __restrict__ idx, int* __restrict__ cursor,
    int* __restrict__ perm, int E)
{
    const int stride = gridDim.x * blockDim.x;
    for (int e = blockIdx.x * blockDim.x + threadIdx.x; e < E; e += stride) {
        const int n = idx[e];
        const int p = atomicAdd(&cursor[n], 1);
        perm[p] = e;
    }
}

// ---------------- pass 4: gather + reduce, one wave per node ---------------
// 64 lanes x float2 = 512 B per edge row (perfectly coalesced). Edge IDs for
// a <=64-edge chunk come from ONE coalesced load (perm[cs+lane]) and are
// broadcast with __shfl; next edge's rbf/x loads are issued before the
// current edge's FMAs (2-deep software pipeline).
__global__ __launch_bounds__(256) void gather_kernel(
    const float* __restrict__ x,
    const float* __restrict__ rbf,
    const float* __restrict__ W,
    const int*   __restrict__ offs,
    const int*   __restrict__ perm,
    float*       __restrict__ out,
    int N)
{
    __shared__ float sW[HIDDEN * NRAD];
    for (int t = threadIdx.x; t < HIDDEN * NRAD; t += blockDim.x) sW[t] = W[t];
    __syncthreads();

    const int lane = threadIdx.x & 63;
    const int h0   = lane * 2;

    float w0[NRAD], w1[NRAD];
#pragma unroll
    for (int r = 0; r < NRAD; ++r) {
        w0[r] = sW[(h0 + 0) * NRAD + r];
        w1[r] = sW[(h0 + 1) * NRAD + r];
    }

    const int wid = blockIdx.x * (blockDim.x >> 6) + (threadIdx.x >> 6);
    const int nw  = gridDim.x * (blockDim.x >> 6);

    for (int n = wid; n < N; n += nw) {
        const int s    = offs[n];
        const int tend = offs[n + 1];
        float accx = 0.f, accy = 0.f;

        for (int cs = s; cs < tend; cs += 64) {
            const int cnt = min(tend - cs, 64);
            const int epack = (lane < cnt) ? perm[cs + lane] : 0;

            // prologue: load edge 0 of the chunk
            int e = __shfl(epack, 0, 64);
            const float2* rp = reinterpret_cast<const float2*>(rbf + (size_t)e * NRAD);
            float2 ra = rp[0], rb = rp[1], rc = rp[2];
            float2 xv = *reinterpret_cast<const float2*>(x + (size_t)e * HIDDEN + h0);

            for (int j = 0; j < cnt; ++j) {
                // prefetch next edge (index clamps to a valid edge id; result
                // discarded on the last iteration -> branch-free inner loop)
                const int ne = __shfl(epack, (j + 1) & 63, 64);
                const float2* np = reinterpret_cast<const float2*>(rbf + (size_t)ne * NRAD);
                const float2 nra = np[0], nrb = np[1], nrc = np[2];
                const float2 nxv = *reinterpret_cast<const float2*>(x + (size_t)ne * HIDDEN + h0);

                const float c0 = w0[0] * ra.x + w0[1] * ra.y + w0[2] * rb.x
                               + w0[3] * rb.y + w0[4] * rc.x + w0[5] * rc.y;
                const float c1 = w1[0] * ra.x + w1[1] * ra.y + w1[2] * rb.x
                               + w1[3] * rb.y + w1[4] * rc.x + w1[5] * rc.y;
                accx += c0 * xv.x;
                accy += c1 * xv.y;

                ra = nra; rb = nrb; rc = nrc; xv = nxv;
            }
        }
        *reinterpret_cast<float2*>(out + (size_t)n * HIDDEN + h0) =
            make_float2(accx, accy);
    }
}

extern "C" void kernel_launch(void* const* d_in, const int* in_sizes, int n_in,
                              void* d_out, int out_size, void* d_ws, size_t ws_size,
                              hipStream_t stream) {
    const float* x   = (const float*)d_in[0];   // [E,128]
    const float* rbf = (const float*)d_in[1];   // [E,6]
    const float* W   = (const float*)d_in[2];   // [128,6]
    const int*   idx = (const int*)d_in[3];     // [E]
    float* out = (float*)d_out;                 // [N,128]

    const int E = in_sizes[3];
    const int N = out_size / HIDDEN;

    // workspace: offs[N+1] | cursor[N] | perm[E]
    const size_t need = sizeof(int) * ((size_t)(N + 1) + (size_t)N + (size_t)E);
    if (d_ws == nullptr || ws_size < need) {
        // fallback: proven atomic path
        hipMemsetAsync(d_out, 0, (size_t)out_size * sizeof(float), stream);
        const int blocks = (E + 7) / 8;
        msg_scatter_kernel<<<blocks, 256, 0, stream>>>(x, rbf, W, idx, out, E);
        return;
    }

    int* offs   = (int*)d_ws;
    int* cursor = offs + (N + 1);
    int* perm   = cursor + N;

    hipMemsetAsync(offs, 0, (size_t)(N + 1) * sizeof(int), stream);
    hist_kernel<<<2048, 256, 0, stream>>>(idx, offs, E);
    scan_kernel<<<1, 1024, 0, stream>>>(offs, cursor, N);
    scatter_kernel<<<2048, 256, 0, stream>>>(idx, cursor, perm, E);

    // one 64-lane wave per node; gather writes EVERY out row (zeros for
    // degree-0 nodes), so no out memset is needed.
    const int gblocks = (N + 3) / 4;
    gather_kernel<<<gblocks, 256, 0, stream>>>(x, rbf, W, offs, perm, out, N);
}